// Round 1
// baseline (1460.278 us; speedup 1.0000x reference)
//
#include <hip/hip_runtime.h>
#include <math.h>

#define N_NODES 20000
#define N_EDGES 320000

__device__ __forceinline__ float lrelu(float x){ return x > 0.f ? x : 0.02f*x; }

// ---------------- CSR build ----------------
__global__ void k_zero(int* counts, float* deg){
  int i = blockIdx.x*blockDim.x + threadIdx.x;
  if (i < N_NODES){ counts[i]=0; deg[i]=0.f; }
}

__global__ void k_count(const int* __restrict__ dst, int* __restrict__ counts){
  int e = blockIdx.x*blockDim.x + threadIdx.x;
  if (e < N_EDGES) atomicAdd(&counts[dst[e]], 1);
}

__global__ void k_scan(int* __restrict__ counts, int* __restrict__ rowptr){
  __shared__ int part[256];
  int tid = threadIdx.x;
  const int CH = (N_NODES + 255)/256; // 79
  int b = tid*CH, e = b+CH; if (e > N_NODES) e = N_NODES;
  int s = 0;
  for (int i=b;i<e;++i) s += counts[i];
  part[tid] = s; __syncthreads();
  if (tid==0){
    int run=0;
    for (int i=0;i<256;++i){ int t=part[i]; part[i]=run; run+=t; }
    rowptr[N_NODES]=run;
  }
  __syncthreads();
  int off = part[tid];
  for (int i=b;i<e;++i){ rowptr[i]=off; off += counts[i]; counts[i]=0; }
}

__global__ void k_fill(const int* __restrict__ src, const int* __restrict__ dst,
                       const int* __restrict__ rowptr, int* __restrict__ cursor,
                       int* __restrict__ srcS, int* __restrict__ dstS){
  int e = blockIdx.x*blockDim.x + threadIdx.x;
  if (e < N_EDGES){
    int d = dst[e];
    int pos = atomicAdd(&cursor[d],1);
    int idx = rowptr[d] + pos;
    srcS[idx] = src[e];
    dstS[idx] = d;
  }
}

// ---------------- GEMM: C[M x ncols] = A[M x 128] @ W[128 x ncols] (+bias)(+lrelu) ----------------
__global__ __launch_bounds__(256) void k_gemm(const float* __restrict__ A,
    const float* __restrict__ W, int wstride, const float* __restrict__ bias,
    float* __restrict__ C, int ncols, int act)
{
  __shared__ float As[128][64];   // [k][r] transposed
  __shared__ float Ws[128][64];   // [k][c]
  int t = threadIdx.x;
  int rbase = blockIdx.x * 64;
  int cbase = blockIdx.y * 64;
  {
    int row = t >> 2, kq = t & 3;
    int grow = rbase + row; if (grow > N_NODES-1) grow = N_NODES-1;
    const float* Ar = A + (size_t)grow*128;
    #pragma unroll
    for (int j=0;j<8;++j){
      int k0 = (kq<<2) + (j<<4);
      float4 v4 = *reinterpret_cast<const float4*>(Ar + k0);
      As[k0+0][row]=v4.x; As[k0+1][row]=v4.y; As[k0+2][row]=v4.z; As[k0+3][row]=v4.w;
    }
    int c = t & 63, kb = t >> 6;
    #pragma unroll
    for (int j=0;j<32;++j){
      int k = kb + (j<<2);
      Ws[k][c] = W[(size_t)k*wstride + cbase + c];
    }
  }
  __syncthreads();
  int r0 = (t>>4)<<2, c0 = (t&15)<<2;
  float acc[4][4] = {};
  #pragma unroll 8
  for (int k=0;k<128;++k){
    float4 a4 = *reinterpret_cast<const float4*>(&As[k][r0]);
    float4 w4 = *reinterpret_cast<const float4*>(&Ws[k][c0]);
    acc[0][0]+=a4.x*w4.x; acc[0][1]+=a4.x*w4.y; acc[0][2]+=a4.x*w4.z; acc[0][3]+=a4.x*w4.w;
    acc[1][0]+=a4.y*w4.x; acc[1][1]+=a4.y*w4.y; acc[1][2]+=a4.y*w4.z; acc[1][3]+=a4.y*w4.w;
    acc[2][0]+=a4.z*w4.x; acc[2][1]+=a4.z*w4.y; acc[2][2]+=a4.z*w4.z; acc[2][3]+=a4.z*w4.w;
    acc[3][0]+=a4.w*w4.x; acc[3][1]+=a4.w*w4.y; acc[3][2]+=a4.w*w4.z; acc[3][3]+=a4.w*w4.w;
  }
  #pragma unroll
  for (int i2=0;i2<4;++i2){
    int grow = rbase + r0 + i2;
    if (grow < N_NODES){
      #pragma unroll
      for (int j2=0;j2<4;++j2){
        int col = cbase + c0 + j2;
        float v = acc[i2][j2] + (bias ? bias[col] : 0.f);
        if (act) v = lrelu(v);
        C[(size_t)grow*ncols + col] = v;
      }
    }
  }
}

// ---------------- per-edge: wlap MLP + r dot; wave per edge ----------------
__global__ __launch_bounds__(256) void k_edge(
    const int* __restrict__ srcS, const int* __restrict__ dstS,
    const float* __restrict__ x,
    const float* __restrict__ P, const float* __restrict__ Q,
    const float* __restrict__ eW1, const float* __restrict__ eb1,
    const float* __restrict__ eW2, const float* __restrict__ eb2,
    const float* __restrict__ rW1, const float* __restrict__ rW2,
    const float* __restrict__ rb2,
    float* __restrict__ deg, float4* __restrict__ rxw)
{
  __shared__ float s_eW1[10*128];
  __shared__ float s_eb1[128], s_eW2[128];
  __shared__ float s_rU[256], s_rW2[256];
  int tid = threadIdx.x;
  for (int i = tid; i < 1280; i += 256) s_eW1[i] = eW1[i];
  if (tid < 128){ s_eb1[tid]=eb1[tid]; s_eW2[tid]=eW2[tid]; }
  for (int i=tid;i<256;i+=256){ s_rU[i]=rW1[256*256+i]; s_rW2[i]=rW2[i]; }
  __syncthreads();
  float eb2v = eb2[0], rb2v = rb2[0];
  int lane = tid & 63;
  int gw = blockIdx.x*4 + (tid>>6);
  int nw = gridDim.x*4;
  const float ISIG[10] = {1e-0f,1e-2f,1e-4f,1e-6f,1e-8f,1e-10f,
                          1e-12f,1e-14f,1e-16f,1e-18f};
  for (int e = gw; e < N_EDGES; e += nw){
    int s = srcS[e], d = dstS[e];
    float xd0 = x[s*3+0]-x[d*3+0];
    float xd1 = x[s*3+1]-x[d*3+1];
    float xd2 = x[s*3+2]-x[d*3+2];
    float d2 = xd0*xd0 + xd1*xd1 + xd2*xd2;
    float g[10];
    #pragma unroll
    for (int j=0;j<10;++j) g[j] = expf(-d2*ISIG[j]);
    int c1 = lane, c2 = lane+64;
    float h1 = s_eb1[c1], h2 = s_eb1[c2];
    #pragma unroll
    for (int j=0;j<10;++j){ h1 += g[j]*s_eW1[j*128+c1]; h2 += g[j]*s_eW1[j*128+c2]; }
    h1 = lrelu(h1); h2 = lrelu(h2);
    float part = h1*s_eW2[c1] + h2*s_eW2[c2];
    #pragma unroll
    for (int m=1;m<64;m<<=1) part += __shfl_xor(part, m);
    float wlap = part + eb2v; wlap = wlap > 0.f ? wlap : 0.f;
    const float* Ps = P + (size_t)s*256;
    const float* Qd = Q + (size_t)d*256;
    float acc = 0.f;
    #pragma unroll
    for (int k=0;k<4;++k){
      int c = lane + 64*k;
      float v = Ps[c] + Qd[c] + wlap*s_rU[c];
      acc += lrelu(v)*s_rW2[c];
    }
    #pragma unroll
    for (int m=1;m<64;m<<=1) acc += __shfl_xor(acc, m);
    float r = acc + rb2v;
    if (lane==0){
      atomicAdd(&deg[s], wlap);
      rxw[e] = make_float4(r*xd0, r*xd1, r*xd2, wlap);
    }
  }
}

__global__ void k_dinv(const float* __restrict__ deg, float* __restrict__ dinv){
  int i = blockIdx.x*blockDim.x + threadIdx.x;
  if (i < N_NODES){ float dg = deg[i]; dinv[i] = dg > 0.f ? 1.0f/sqrtf(dg) : 0.f; }
}

__global__ void k_normE(const int* __restrict__ srcS, const int* __restrict__ dstS,
                        const float4* __restrict__ rxw, const float* __restrict__ dinv,
                        float* __restrict__ norm){
  int e = blockIdx.x*blockDim.x + threadIdx.x;
  if (e < N_EDGES) norm[e] = dinv[srcS[e]] * rxw[e].w * dinv[dstS[e]];
}

// agg pull: wave per node
__global__ __launch_bounds__(256) void k_agg(const int* __restrict__ rowptr,
    const float4* __restrict__ rxw, const float* __restrict__ x, float* __restrict__ outX){
  int lane = threadIdx.x & 63;
  int v = blockIdx.x*4 + (threadIdx.x>>6);
  if (v >= N_NODES) return;
  int b = rowptr[v], e = rowptr[v+1];
  float a0=0.f,a1=0.f,a2=0.f;
  for (int i=b+lane;i<e;i+=64){ float4 f = rxw[i]; a0+=f.x; a1+=f.y; a2+=f.z; }
  #pragma unroll
  for (int m=1;m<64;m<<=1){ a0+=__shfl_xor(a0,m); a1+=__shfl_xor(a1,m); a2+=__shfl_xor(a2,m); }
  if (lane==0){
    int cnt = e-b; if (cnt < 1) cnt = 1;
    float inv = 1.0f/(float)cnt;
    outX[v*3+0] = x[v*3+0] + a0*inv;
    outX[v*3+1] = x[v*3+1] + a1*inv;
    outX[v*3+2] = x[v*3+2] + a2*inv;
  }
}

// polynomial coefficients: out = sum_j a_j A^j h0 ; also writes T outputs
__global__ void k_coef(const float* __restrict__ temp, float* __restrict__ coef,
                       float* __restrict__ outT1, float* __restrict__ outT2){
  if (threadIdx.x == 0 && blockIdx.x == 0){
    const double binom[11] = {1,10,45,120,210,252,210,120,45,10,1};
    double a[11]; for (int j=0;j<11;++j) a[j]=0.0;
    for (int m=0;m<=10;++m){
      double p[11]; p[0]=1.0; for (int j=1;j<11;++j) p[j]=0.0;
      for (int r2=0;r2<10-m;++r2) for (int j=10;j>=1;--j) p[j]+=p[j-1];
      for (int r2=0;r2<m;++r2)    for (int j=10;j>=1;--j) p[j]-=p[j-1];
      float t = temp[m];
      double c = (binom[m]/1024.0) * (t > 0.f ? (double)t : 0.0);
      for (int j=0;j<11;++j) a[j]+=c*p[j];
    }
    for (int j=0;j<11;++j) coef[j]=(float)a[j];
  }
  int i = threadIdx.x;
  if (blockIdx.x==0 && i < 11){ float t = temp[i]; t = t>0.f?t:0.f; outT1[i]=t; outT2[i]=t; }
}

__global__ void k_initz(const float* __restrict__ h0, const float* __restrict__ coef,
                        float* __restrict__ z){
  int i = blockIdx.x*blockDim.x + threadIdx.x;
  if (i < N_NODES*128) z[i] = coef[10]*h0[i];
}

// zout[v] = coef[j]*h0[v] + sum_{in-edges} norm_e * zin[src]
__global__ __launch_bounds__(256) void k_ax(const int* __restrict__ rowptr,
    const int* __restrict__ srcS, const float* __restrict__ norm,
    const float* __restrict__ zin, const float* __restrict__ h0,
    const float* __restrict__ coef, int j, float* __restrict__ zout)
{
  int v = blockIdx.x*2 + (threadIdx.x>>7);
  int t = threadIdx.x & 127;
  if (v >= N_NODES) return;
  float c = coef[j];
  int b = rowptr[v], e = rowptr[v+1];
  float acc0 = c * h0[(size_t)v*128 + t];
  float acc1 = 0.f;
  int i = b;
  for (; i+1 < e; i += 2){
    int s0 = srcS[i], s1 = srcS[i+1];
    float n0 = norm[i], n1 = norm[i+1];
    acc0 += n0 * zin[(size_t)s0*128 + t];
    acc1 += n1 * zin[(size_t)s1*128 + t];
  }
  if (i < e) acc0 += norm[i]*zin[(size_t)srcS[i]*128 + t];
  zout[(size_t)v*128 + t] = acc0 + acc1;
}

extern "C" void kernel_launch(void* const* d_in, const int* in_sizes, int n_in,
                              void* d_out, int out_size, void* d_ws, size_t ws_size,
                              hipStream_t stream) {
  const float* x1  = (const float*)d_in[0];
  const float* h1  = (const float*)d_in[1];
  const float* x2  = (const float*)d_in[2];
  const float* h2  = (const float*)d_in[3];
  const float* eW1 = (const float*)d_in[4];
  const float* eb1 = (const float*)d_in[5];
  const float* eW2 = (const float*)d_in[6];
  const float* eb2 = (const float*)d_in[7];
  const float* rW1 = (const float*)d_in[8];
  const float* rb1 = (const float*)d_in[9];
  const float* rW2 = (const float*)d_in[10];
  const float* rb2 = (const float*)d_in[11];
  const float* fW1 = (const float*)d_in[12];
  const float* fb1 = (const float*)d_in[13];
  const float* fW2 = (const float*)d_in[14];
  const float* fb2 = (const float*)d_in[15];
  const float* temp= (const float*)d_in[16];
  const int* ei1 = (const int*)d_in[17];
  const int* ei2 = (const int*)d_in[18];

  float* out = (float*)d_out;
  float* outX1 = out;
  float* outH1 = out + 60000;
  float* outX2 = out + 2620000;
  float* outH2 = out + 2680000;
  float* outT1 = out + 5240000;
  float* outT2 = out + 5240011;

  char* ws = (char*)d_ws;
  size_t off = 0;
  auto alloc = [&](size_t bytes)->void*{
    void* p = ws + off; off += (bytes + 255) & ~(size_t)255; return p;
  };
  float* P      = (float*)alloc((size_t)N_NODES*256*4);  // later: [tbuf | z1]
  float* Q      = (float*)alloc((size_t)N_NODES*256*4);  // later: [h0 | z0]
  int*   srcS   = (int*)  alloc((size_t)N_EDGES*4);
  int*   dstS   = (int*)  alloc((size_t)N_EDGES*4);
  float* normE  = (float*)alloc((size_t)N_EDGES*4);
  float4* rxw   = (float4*)alloc((size_t)N_EDGES*16);
  int*   counts = (int*)  alloc((size_t)N_NODES*4);
  int*   rowptr = (int*)  alloc((size_t)(N_NODES+1)*4);
  float* deg    = (float*)alloc((size_t)N_NODES*4);
  float* dinv   = (float*)alloc((size_t)N_NODES*4);
  float* coef   = (float*)alloc(64);

  float* tbuf = P;
  float* z1   = P + (size_t)N_NODES*128;
  float* h0   = Q;
  float* z0   = Q + (size_t)N_NODES*128;

  // polynomial coefficients + T outputs (shared by both graphs)
  k_coef<<<1, 64, 0, stream>>>(temp, coef, outT1, outT2);

  const int EB = (N_EDGES + 255)/256;   // 1250
  const int NB = (N_NODES + 255)/256;   // 79

  for (int g = 0; g < 2; ++g){
    const float* x = g ? x2 : x1;
    const float* h = g ? h2 : h1;
    const int* src = g ? ei2 : ei1;
    const int* dst = src + N_EDGES;
    float* outX = g ? outX2 : outX1;
    float* outH = g ? outH2 : outH1;

    // CSR by dst
    k_zero <<<NB, 256, 0, stream>>>(counts, deg);
    k_count<<<EB, 256, 0, stream>>>(dst, counts);
    k_scan <<<1, 256, 0, stream>>>(counts, rowptr);
    k_fill <<<EB, 256, 0, stream>>>(src, dst, rowptr, counts, srcS, dstS);

    // P = h@rW1[0:128] + rb1 ; Q = h@rW1[128:256]
    k_gemm<<<dim3(313,4), 256, 0, stream>>>(h, rW1,          256, rb1,     P, 256, 0);
    k_gemm<<<dim3(313,4), 256, 0, stream>>>(h, rW1+128*256,  256, nullptr, Q, 256, 0);

    // per-edge wlap + r
    k_edge<<<4096, 256, 0, stream>>>(srcS, dstS, x, P, Q, eW1, eb1, eW2, eb2,
                                     rW1, rW2, rb2, deg, rxw);
    k_dinv <<<NB, 256, 0, stream>>>(deg, dinv);
    k_normE<<<EB, 256, 0, stream>>>(srcS, dstS, rxw, dinv, normE);

    // x output
    k_agg<<<5000, 256, 0, stream>>>(rowptr, rxw, x, outX);

    // h0 = mlp2(h, fW1, fb1, fW2, fb2)   (P region is dead now)
    k_gemm<<<dim3(313,2), 256, 0, stream>>>(h,    fW1, 128, fb1, tbuf, 128, 1);
    k_gemm<<<dim3(313,2), 256, 0, stream>>>(tbuf, fW2, 128, fb2, h0,   128, 0);

    // Horner: z = a10*h0 ; z = A z + a_j h0 for j=9..0
    k_initz<<<10000, 256, 0, stream>>>(h0, coef, z0);
    float* zi = z0; float* zo = z1;
    for (int j = 9; j >= 1; --j){
      k_ax<<<10000, 256, 0, stream>>>(rowptr, srcS, normE, zi, h0, coef, j, zo);
      float* tswap = zi; zi = zo; zo = tswap;
    }
    k_ax<<<10000, 256, 0, stream>>>(rowptr, srcS, normE, zi, h0, coef, 0, outH);
  }
  (void)in_sizes; (void)n_in; (void)out_size; (void)ws_size;
}

// Round 2
// 683.079 us; speedup vs baseline: 2.1378x; 2.1378x over previous
//
#include <hip/hip_runtime.h>
#include <math.h>

#define N_NODES 20000
#define N_EDGES 320000

__device__ __forceinline__ float lrelu(float x){ return x > 0.f ? x : 0.02f*x; }

// ---------------- CSR build ----------------
__global__ void k_zero(int* counts, float* deg){
  int i = blockIdx.x*blockDim.x + threadIdx.x;
  if (i < N_NODES){ counts[i]=0; deg[i]=0.f; }
}

__global__ void k_count(const int* __restrict__ dst, int* __restrict__ counts){
  int e = blockIdx.x*blockDim.x + threadIdx.x;
  if (e < N_EDGES) atomicAdd(&counts[dst[e]], 1);
}

__global__ void k_scan(int* __restrict__ counts, int* __restrict__ rowptr){
  __shared__ int part[256];
  int tid = threadIdx.x;
  const int CH = (N_NODES + 255)/256; // 79
  int b = tid*CH, e = b+CH; if (e > N_NODES) e = N_NODES;
  int s = 0;
  for (int i=b;i<e;++i) s += counts[i];
  part[tid] = s; __syncthreads();
  if (tid==0){
    int run=0;
    for (int i=0;i<256;++i){ int t=part[i]; part[i]=run; run+=t; }
    rowptr[N_NODES]=run;
  }
  __syncthreads();
  int off = part[tid];
  for (int i=b;i<e;++i){ rowptr[i]=off; off += counts[i]; counts[i]=0; }
}

__global__ void k_fill(const int* __restrict__ src, const int* __restrict__ dst,
                       const int* __restrict__ rowptr, int* __restrict__ cursor,
                       int* __restrict__ srcS, int* __restrict__ dstS){
  int e = blockIdx.x*blockDim.x + threadIdx.x;
  if (e < N_EDGES){
    int d = dst[e];
    int pos = atomicAdd(&cursor[d],1);
    int idx = rowptr[d] + pos;
    srcS[idx] = src[e];
    dstS[idx] = d;
  }
}

// ---------------- GEMM: C[M x ncols] = A[M x 128] @ W[128 x ncols] (+bias)(+lrelu) ----------------
__global__ __launch_bounds__(256) void k_gemm(const float* __restrict__ A,
    const float* __restrict__ W, int wstride, const float* __restrict__ bias,
    float* __restrict__ C, int ncols, int act)
{
  __shared__ float As[128][64];   // [k][r] transposed
  __shared__ float Ws[128][64];   // [k][c]
  int t = threadIdx.x;
  int rbase = blockIdx.x * 64;
  int cbase = blockIdx.y * 64;
  {
    int row = t >> 2, kq = t & 3;
    int grow = rbase + row; if (grow > N_NODES-1) grow = N_NODES-1;
    const float* Ar = A + (size_t)grow*128;
    #pragma unroll
    for (int j=0;j<8;++j){
      int k0 = (kq<<2) + (j<<4);
      float4 v4 = *reinterpret_cast<const float4*>(Ar + k0);
      As[k0+0][row]=v4.x; As[k0+1][row]=v4.y; As[k0+2][row]=v4.z; As[k0+3][row]=v4.w;
    }
    int c = t & 63, kb = t >> 6;
    #pragma unroll
    for (int j=0;j<32;++j){
      int k = kb + (j<<2);
      Ws[k][c] = W[(size_t)k*wstride + cbase + c];
    }
  }
  __syncthreads();
  int r0 = (t>>4)<<2, c0 = (t&15)<<2;
  float acc[4][4] = {};
  #pragma unroll 8
  for (int k=0;k<128;++k){
    float4 a4 = *reinterpret_cast<const float4*>(&As[k][r0]);
    float4 w4 = *reinterpret_cast<const float4*>(&Ws[k][c0]);
    acc[0][0]+=a4.x*w4.x; acc[0][1]+=a4.x*w4.y; acc[0][2]+=a4.x*w4.z; acc[0][3]+=a4.x*w4.w;
    acc[1][0]+=a4.y*w4.x; acc[1][1]+=a4.y*w4.y; acc[1][2]+=a4.y*w4.z; acc[1][3]+=a4.y*w4.w;
    acc[2][0]+=a4.z*w4.x; acc[2][1]+=a4.z*w4.y; acc[2][2]+=a4.z*w4.z; acc[2][3]+=a4.z*w4.w;
    acc[3][0]+=a4.w*w4.x; acc[3][1]+=a4.w*w4.y; acc[3][2]+=a4.w*w4.z; acc[3][3]+=a4.w*w4.w;
  }
  #pragma unroll
  for (int i2=0;i2<4;++i2){
    int grow = rbase + r0 + i2;
    if (grow < N_NODES){
      #pragma unroll
      for (int j2=0;j2<4;++j2){
        int col = cbase + c0 + j2;
        float v = acc[i2][j2] + (bias ? bias[col] : 0.f);
        if (act) v = lrelu(v);
        C[(size_t)grow*ncols + col] = v;
      }
    }
  }
}

// ---------------- per-edge: wlap MLP + r dot; wave per edge ----------------
__global__ __launch_bounds__(256) void k_edge(
    const int* __restrict__ srcS, const int* __restrict__ dstS,
    const float* __restrict__ x,
    const float* __restrict__ P, const float* __restrict__ Q,
    const float* __restrict__ eW1, const float* __restrict__ eb1,
    const float* __restrict__ eW2, const float* __restrict__ eb2,
    const float* __restrict__ rW1, const float* __restrict__ rW2,
    const float* __restrict__ rb2,
    float* __restrict__ deg, float4* __restrict__ rxw)
{
  __shared__ float s_eW1[10*128];
  __shared__ float s_eb1[128], s_eW2[128];
  __shared__ float s_rU[256], s_rW2[256];
  int tid = threadIdx.x;
  for (int i = tid; i < 1280; i += 256) s_eW1[i] = eW1[i];
  if (tid < 128){ s_eb1[tid]=eb1[tid]; s_eW2[tid]=eW2[tid]; }
  for (int i=tid;i<256;i+=256){ s_rU[i]=rW1[256*256+i]; s_rW2[i]=rW2[i]; }
  __syncthreads();
  float eb2v = eb2[0], rb2v = rb2[0];
  int lane = tid & 63;
  int gw = blockIdx.x*4 + (tid>>6);
  int nw = gridDim.x*4;
  const float ISIG[10] = {1e-0f,1e-2f,1e-4f,1e-6f,1e-8f,1e-10f,
                          1e-12f,1e-14f,1e-16f,1e-18f};
  for (int e = gw; e < N_EDGES; e += nw){
    int s = srcS[e], d = dstS[e];
    // issue the wide gathers early; they don't depend on wlap
    const float4 p4 = *reinterpret_cast<const float4*>(P + (size_t)s*256 + lane*4);
    const float4 q4 = *reinterpret_cast<const float4*>(Q + (size_t)d*256 + lane*4);
    float xd0 = x[s*3+0]-x[d*3+0];
    float xd1 = x[s*3+1]-x[d*3+1];
    float xd2 = x[s*3+2]-x[d*3+2];
    float d2 = xd0*xd0 + xd1*xd1 + xd2*xd2;
    float g[10];
    #pragma unroll
    for (int j=0;j<10;++j) g[j] = __expf(-d2*ISIG[j]);   // v_exp_f32 fast path
    int c1 = lane, c2 = lane+64;
    float h1 = s_eb1[c1], h2 = s_eb1[c2];
    #pragma unroll
    for (int j=0;j<10;++j){ h1 += g[j]*s_eW1[j*128+c1]; h2 += g[j]*s_eW1[j*128+c2]; }
    h1 = lrelu(h1); h2 = lrelu(h2);
    float part = h1*s_eW2[c1] + h2*s_eW2[c2];
    #pragma unroll
    for (int m=1;m<64;m<<=1) part += __shfl_xor(part, m);
    float wlap = part + eb2v; wlap = wlap > 0.f ? wlap : 0.f;
    const float4 u4 = *reinterpret_cast<const float4*>(s_rU + lane*4);
    const float4 w4 = *reinterpret_cast<const float4*>(s_rW2 + lane*4);
    float acc = lrelu(p4.x + q4.x + wlap*u4.x) * w4.x
              + lrelu(p4.y + q4.y + wlap*u4.y) * w4.y
              + lrelu(p4.z + q4.z + wlap*u4.z) * w4.z
              + lrelu(p4.w + q4.w + wlap*u4.w) * w4.w;
    #pragma unroll
    for (int m=1;m<64;m<<=1) acc += __shfl_xor(acc, m);
    float r = acc + rb2v;
    if (lane==0){
      atomicAdd(&deg[s], wlap);
      rxw[e] = make_float4(r*xd0, r*xd1, r*xd2, wlap);
    }
  }
}

__global__ void k_dinv(const float* __restrict__ deg, float* __restrict__ dinv){
  int i = blockIdx.x*blockDim.x + threadIdx.x;
  if (i < N_NODES){ float dg = deg[i]; dinv[i] = dg > 0.f ? 1.0f/sqrtf(dg) : 0.f; }
}

__global__ void k_normE(const int* __restrict__ srcS, const int* __restrict__ dstS,
                        const float4* __restrict__ rxw, const float* __restrict__ dinv,
                        float* __restrict__ norm){
  int e = blockIdx.x*blockDim.x + threadIdx.x;
  if (e < N_EDGES) norm[e] = dinv[srcS[e]] * rxw[e].w * dinv[dstS[e]];
}

// agg pull: wave per node
__global__ __launch_bounds__(256) void k_agg(const int* __restrict__ rowptr,
    const float4* __restrict__ rxw, const float* __restrict__ x, float* __restrict__ outX){
  int lane = threadIdx.x & 63;
  int v = blockIdx.x*4 + (threadIdx.x>>6);
  if (v >= N_NODES) return;
  int b = rowptr[v], e = rowptr[v+1];
  float a0=0.f,a1=0.f,a2=0.f;
  for (int i=b+lane;i<e;i+=64){ float4 f = rxw[i]; a0+=f.x; a1+=f.y; a2+=f.z; }
  #pragma unroll
  for (int m=1;m<64;m<<=1){ a0+=__shfl_xor(a0,m); a1+=__shfl_xor(a1,m); a2+=__shfl_xor(a2,m); }
  if (lane==0){
    int cnt = e-b; if (cnt < 1) cnt = 1;
    float inv = 1.0f/(float)cnt;
    outX[v*3+0] = x[v*3+0] + a0*inv;
    outX[v*3+1] = x[v*3+1] + a1*inv;
    outX[v*3+2] = x[v*3+2] + a2*inv;
  }
}

// polynomial coefficients: out = sum_j a_j A^j h0 ; also writes T outputs
__global__ void k_coef(const float* __restrict__ temp, float* __restrict__ coef,
                       float* __restrict__ outT1, float* __restrict__ outT2){
  if (threadIdx.x == 0 && blockIdx.x == 0){
    const double binom[11] = {1,10,45,120,210,252,210,120,45,10,1};
    double a[11]; for (int j=0;j<11;++j) a[j]=0.0;
    for (int m=0;m<=10;++m){
      double p[11]; p[0]=1.0; for (int j=1;j<11;++j) p[j]=0.0;
      for (int r2=0;r2<10-m;++r2) for (int j=10;j>=1;--j) p[j]+=p[j-1];
      for (int r2=0;r2<m;++r2)    for (int j=10;j>=1;--j) p[j]-=p[j-1];
      float t = temp[m];
      double c = (binom[m]/1024.0) * (t > 0.f ? (double)t : 0.0);
      for (int j=0;j<11;++j) a[j]+=c*p[j];
    }
    for (int j=0;j<11;++j) coef[j]=(float)a[j];
  }
  int i = threadIdx.x;
  if (blockIdx.x==0 && i < 11){ float t = temp[i]; t = t>0.f?t:0.f; outT1[i]=t; outT2[i]=t; }
}

// z0 = coef[10]*h0 — skip entirely if coef[10]==0 (consumer will not read, by the
// same zero-sum guard logic used in k_ax)
__global__ void k_initz(const float* __restrict__ h0, const float* __restrict__ coef,
                        float* __restrict__ z){
  if (coef[10] == 0.f) return;
  int i = blockIdx.x*blockDim.x + threadIdx.x;
  if (i < N_NODES*128) z[i] = coef[10]*h0[i];
}

// zout[v] = coef[j]*h0[v] + sum_{in-edges} norm_e * zin[src]
// Zero-sum guards (exact, generic): zin == 0 iff coef[m]==0 for all m>j;
// zout == 0 iff coef[m]==0 for all m>=j. Producer skips the write exactly when
// the consumer's guard will skip the read — consistent for any temp values.
__global__ __launch_bounds__(256) void k_ax(const int* __restrict__ rowptr,
    const int* __restrict__ srcS, const float* __restrict__ norm,
    const float* __restrict__ zin, const float* __restrict__ h0,
    const float* __restrict__ coef, int j, float* __restrict__ zout)
{
  float sIn = 0.f;
  for (int m = j+1; m <= 10; ++m) sIn += fabsf(coef[m]);
  float c = coef[j];
  float sOut = sIn + fabsf(c);
  if (sOut == 0.f) return;                       // output identically zero: skip write
  int v = blockIdx.x*2 + (threadIdx.x>>7);
  int t = threadIdx.x & 127;
  if (v >= N_NODES) return;
  if (sIn == 0.f){                               // zin identically zero: pure scale
    zout[(size_t)v*128 + t] = c * h0[(size_t)v*128 + t];
    return;
  }
  int b = rowptr[v], e = rowptr[v+1];
  float acc0 = c * h0[(size_t)v*128 + t];
  float acc1 = 0.f;
  int i = b;
  for (; i+1 < e; i += 2){
    int s0 = srcS[i], s1 = srcS[i+1];
    float n0 = norm[i], n1 = norm[i+1];
    acc0 += n0 * zin[(size_t)s0*128 + t];
    acc1 += n1 * zin[(size_t)s1*128 + t];
  }
  if (i < e) acc0 += norm[i]*zin[(size_t)srcS[i]*128 + t];
  zout[(size_t)v*128 + t] = acc0 + acc1;
}

extern "C" void kernel_launch(void* const* d_in, const int* in_sizes, int n_in,
                              void* d_out, int out_size, void* d_ws, size_t ws_size,
                              hipStream_t stream) {
  const float* x1  = (const float*)d_in[0];
  const float* h1  = (const float*)d_in[1];
  const float* x2  = (const float*)d_in[2];
  const float* h2  = (const float*)d_in[3];
  const float* eW1 = (const float*)d_in[4];
  const float* eb1 = (const float*)d_in[5];
  const float* eW2 = (const float*)d_in[6];
  const float* eb2 = (const float*)d_in[7];
  const float* rW1 = (const float*)d_in[8];
  const float* rb1 = (const float*)d_in[9];
  const float* rW2 = (const float*)d_in[10];
  const float* rb2 = (const float*)d_in[11];
  const float* fW1 = (const float*)d_in[12];
  const float* fb1 = (const float*)d_in[13];
  const float* fW2 = (const float*)d_in[14];
  const float* fb2 = (const float*)d_in[15];
  const float* temp= (const float*)d_in[16];
  const int* ei1 = (const int*)d_in[17];
  const int* ei2 = (const int*)d_in[18];

  float* out = (float*)d_out;
  float* outX1 = out;
  float* outH1 = out + 60000;
  float* outX2 = out + 2620000;
  float* outH2 = out + 2680000;
  float* outT1 = out + 5240000;
  float* outT2 = out + 5240011;

  char* ws = (char*)d_ws;
  size_t off = 0;
  auto alloc = [&](size_t bytes)->void*{
    void* p = ws + off; off += (bytes + 255) & ~(size_t)255; return p;
  };
  float* P      = (float*)alloc((size_t)N_NODES*256*4);  // later: [tbuf | z1]
  float* Q      = (float*)alloc((size_t)N_NODES*256*4);  // later: [h0 | z0]
  int*   srcS   = (int*)  alloc((size_t)N_EDGES*4);
  int*   dstS   = (int*)  alloc((size_t)N_EDGES*4);
  float* normE  = (float*)alloc((size_t)N_EDGES*4);
  float4* rxw   = (float4*)alloc((size_t)N_EDGES*16);
  int*   counts = (int*)  alloc((size_t)N_NODES*4);
  int*   rowptr = (int*)  alloc((size_t)(N_NODES+1)*4);
  float* deg    = (float*)alloc((size_t)N_NODES*4);
  float* dinv   = (float*)alloc((size_t)N_NODES*4);
  float* coef   = (float*)alloc(64);

  float* tbuf = P;
  float* z1   = P + (size_t)N_NODES*128;
  float* h0   = Q;
  float* z0   = Q + (size_t)N_NODES*128;

  // polynomial coefficients + T outputs (shared by both graphs)
  k_coef<<<1, 64, 0, stream>>>(temp, coef, outT1, outT2);

  const int EB = (N_EDGES + 255)/256;   // 1250
  const int NB = (N_NODES + 255)/256;   // 79

  for (int g = 0; g < 2; ++g){
    const float* x = g ? x2 : x1;
    const float* h = g ? h2 : h1;
    const int* src = g ? ei2 : ei1;
    const int* dst = src + N_EDGES;
    float* outX = g ? outX2 : outX1;
    float* outH = g ? outH2 : outH1;

    // CSR by dst
    k_zero <<<NB, 256, 0, stream>>>(counts, deg);
    k_count<<<EB, 256, 0, stream>>>(dst, counts);
    k_scan <<<1, 256, 0, stream>>>(counts, rowptr);
    k_fill <<<EB, 256, 0, stream>>>(src, dst, rowptr, counts, srcS, dstS);

    // P = h@rW1[0:128] + rb1 ; Q = h@rW1[128:256]
    k_gemm<<<dim3(313,4), 256, 0, stream>>>(h, rW1,          256, rb1,     P, 256, 0);
    k_gemm<<<dim3(313,4), 256, 0, stream>>>(h, rW1+128*256,  256, nullptr, Q, 256, 0);

    // per-edge wlap + r
    k_edge<<<4096, 256, 0, stream>>>(srcS, dstS, x, P, Q, eW1, eb1, eW2, eb2,
                                     rW1, rW2, rb2, deg, rxw);
    k_dinv <<<NB, 256, 0, stream>>>(deg, dinv);
    k_normE<<<EB, 256, 0, stream>>>(srcS, dstS, rxw, dinv, normE);

    // x output
    k_agg<<<5000, 256, 0, stream>>>(rowptr, rxw, x, outX);

    // h0 = mlp2(h, fW1, fb1, fW2, fb2)   (P region is dead now)
    k_gemm<<<dim3(313,2), 256, 0, stream>>>(h,    fW1, 128, fb1, tbuf, 128, 1);
    k_gemm<<<dim3(313,2), 256, 0, stream>>>(tbuf, fW2, 128, fb2, h0,   128, 0);

    // Horner: z = a10*h0 ; z = A z + a_j h0 for j=9..0  (zero-coef steps skip)
    k_initz<<<10000, 256, 0, stream>>>(h0, coef, z0);
    float* zi = z0; float* zo = z1;
    for (int j = 9; j >= 1; --j){
      k_ax<<<10000, 256, 0, stream>>>(rowptr, srcS, normE, zi, h0, coef, j, zo);
      float* tswap = zi; zi = zo; zo = tswap;
    }
    k_ax<<<10000, 256, 0, stream>>>(rowptr, srcS, normE, zi, h0, coef, 0, outH);
  }
  (void)in_sizes; (void)n_in; (void)out_size; (void)ws_size;
}

// Round 3
// 578.387 us; speedup vs baseline: 2.5247x; 1.1810x over previous
//
#include <hip/hip_runtime.h>
#include <math.h>

#define N_NODES 20000
#define N_EDGES 320000

__device__ __forceinline__ float lrelu(float x){ return x > 0.f ? x : 0.02f*x; }

__device__ __forceinline__ unsigned short f2bf(float f){
  union { float f; unsigned u; } v; v.f = f;
  unsigned r = (v.u + 0x7FFFu + ((v.u >> 16) & 1u)) >> 16;
  return (unsigned short)r;
}

typedef __attribute__((ext_vector_type(8))) short bf16x8;
typedef __attribute__((ext_vector_type(4))) float f32x4;

// ---------------- CSR build ----------------
__global__ void k_zero(int* counts, float* deg){
  int i = blockIdx.x*blockDim.x + threadIdx.x;
  if (i < N_NODES){ counts[i]=0; deg[i]=0.f; }
}

__global__ void k_count(const int* __restrict__ dst, int* __restrict__ counts){
  int e = blockIdx.x*blockDim.x + threadIdx.x;
  if (e < N_EDGES) atomicAdd(&counts[dst[e]], 1);
}

__global__ void k_scan(int* __restrict__ counts, int* __restrict__ rowptr){
  __shared__ int part[256];
  int tid = threadIdx.x;
  const int CH = (N_NODES + 255)/256; // 79
  int b = tid*CH, e = b+CH; if (e > N_NODES) e = N_NODES;
  int s = 0;
  for (int i=b;i<e;++i) s += counts[i];
  part[tid] = s; __syncthreads();
  if (tid==0){
    int run=0;
    for (int i=0;i<256;++i){ int t=part[i]; part[i]=run; run+=t; }
    rowptr[N_NODES]=run;
  }
  __syncthreads();
  int off = part[tid];
  for (int i=b;i<e;++i){ rowptr[i]=off; off += counts[i]; counts[i]=0; }
}

__global__ void k_fill(const int* __restrict__ src, const int* __restrict__ dst,
                       const int* __restrict__ rowptr, int* __restrict__ cursor,
                       int* __restrict__ srcS, int* __restrict__ dstS){
  int e = blockIdx.x*blockDim.x + threadIdx.x;
  if (e < N_EDGES){
    int d = dst[e];
    int pos = atomicAdd(&cursor[d],1);
    int idx = rowptr[d] + pos;
    srcS[idx] = src[e];
    dstS[idx] = d;
  }
}

// ---------------- weight prep: WT[N][K] bf16 transposes (once) ----------------
__global__ void k_prep(const float* __restrict__ rW1, const float* __restrict__ fW1,
                       const float* __restrict__ fW2,
                       unsigned short* __restrict__ WTpq,
                       unsigned short* __restrict__ WTf1,
                       unsigned short* __restrict__ WTf2){
  int i = blockIdx.x*blockDim.x + threadIdx.x;   // 98304 total
  if (i < 65536){
    int c = i >> 7, k = i & 127;
    float v = (c < 256) ? rW1[(size_t)k*256 + c] : rW1[(size_t)(128+k)*256 + (c-256)];
    WTpq[i] = f2bf(v);
  } else if (i < 81920){
    int j = i - 65536; int n = j >> 7, k = j & 127;
    WTf1[j] = f2bf(fW1[(size_t)k*128 + n]);
  } else if (i < 98304){
    int j = i - 81920; int n = j >> 7, k = j & 127;
    WTf2[j] = f2bf(fW2[(size_t)k*128 + n]);
  }
}

// ---------------- f32 -> bf16 convert (per-graph h) ----------------
__global__ void k_tobf16(const float* __restrict__ in, unsigned short* __restrict__ outp){
  int i = blockIdx.x*blockDim.x + threadIdx.x;   // n4 = 640000
  if (i < N_NODES*128/4){
    float4 v = reinterpret_cast<const float4*>(in)[i];
    ushort4 o;
    o.x = f2bf(v.x); o.y = f2bf(v.y); o.z = f2bf(v.z); o.w = f2bf(v.w);
    reinterpret_cast<ushort4*>(outp)[i] = o;
  }
}

// ---------------- MFMA bf16 GEMM: C[M x N] = A_bf[M x 128] @ WT^T ----------------
// WT is [N][128] bf16 row-major. 64x64 tile, 4 waves, 16x16x32 MFMA.
// mode 0: N=512, col<256 -> O1=v+bias[col] (P), else O2=v (Q), both f32 stride 256
// mode 1: N=128, Ob = bf16(lrelu(v+bias[col]))
// mode 2: N=128, O1 = v+bias[col] (f32 stride 128)
__global__ __launch_bounds__(256) void k_gemm_mfma(
    const unsigned short* __restrict__ Abf, const unsigned short* __restrict__ WT,
    const float* __restrict__ bias, int mode,
    float* __restrict__ O1, float* __restrict__ O2, unsigned short* __restrict__ Ob)
{
  __shared__ char lA[16384];
  __shared__ char lB[16384];
  int t = threadIdx.x;
  int rbase = blockIdx.x * 64;
  int cbase = blockIdx.y * 64;
  #pragma unroll
  for (int i=0;i<4;++i){
    int c = t + i*256;            // chunk 0..1023, 16B each
    int row = c >> 4, c8 = c & 15;
    int grow = rbase + row; if (grow > N_NODES-1) grow = N_NODES-1;
    float4 av = *reinterpret_cast<const float4*>(Abf + (size_t)grow*128 + c8*8);
    *reinterpret_cast<float4*>(lA + (((row<<8) + (c8<<4)) ^ ((row&7)<<4))) = av;
    float4 wv = *reinterpret_cast<const float4*>(WT + (size_t)(cbase+row)*128 + c8*8);
    *reinterpret_cast<float4*>(lB + (((row<<8) + (c8<<4)) ^ ((row&7)<<4))) = wv;
  }
  __syncthreads();
  int l = t & 63, w = t >> 6;
  int lr = l & 15;
  int lkb = ((l >> 4) << 3) * 2;          // k byte offset within 32-k step: 0,16,32,48
  int sxor = (lr & 7) << 4;
  f32x4 acc[4];
  #pragma unroll
  for (int tm=0;tm<4;++tm) acc[tm] = (f32x4){0.f,0.f,0.f,0.f};
  #pragma unroll
  for (int ks=0; ks<4; ++ks){
    int kb = ks*64 + lkb;
    bf16x8 bv = *reinterpret_cast<const bf16x8*>(lB + (((((w<<4)+lr)<<8) + kb) ^ sxor));
    #pragma unroll
    for (int tm=0;tm<4;++tm){
      bf16x8 av = *reinterpret_cast<const bf16x8*>(lA + (((((tm<<4)+lr)<<8) + kb) ^ sxor));
      acc[tm] = __builtin_amdgcn_mfma_f32_16x16x32_bf16(av, bv, acc[tm], 0, 0, 0);
    }
  }
  int col = cbase + (w<<4) + lr;
  float bval = (mode==0) ? (col < 256 ? bias[col] : 0.f) : bias[col];
  int rsub = (l >> 4) << 2;
  #pragma unroll
  for (int tm=0;tm<4;++tm){
    #pragma unroll
    for (int r=0;r<4;++r){
      int grow = rbase + (tm<<4) + rsub + r;
      if (grow < N_NODES){
        float v = acc[tm][r];
        if (mode==0){
          if (col < 256) O1[(size_t)grow*256 + col] = v + bval;
          else           O2[(size_t)grow*256 + col - 256] = v;
        } else if (mode==1){
          Ob[(size_t)grow*128 + col] = f2bf(lrelu(v + bval));
        } else {
          O1[(size_t)grow*128 + col] = v + bval;
        }
      }
    }
  }
}

// ---------------- per-edge: wlap MLP + r dot; wave per edge, pipelined ----------------
__global__ __launch_bounds__(256) void k_edge(
    const int* __restrict__ srcS, const int* __restrict__ dstS,
    const float* __restrict__ x,
    const float* __restrict__ P, const float* __restrict__ Q,
    const float* __restrict__ eW1, const float* __restrict__ eb1,
    const float* __restrict__ eW2, const float* __restrict__ eb2,
    const float* __restrict__ rW1, const float* __restrict__ rW2,
    const float* __restrict__ rb2,
    float* __restrict__ deg, float4* __restrict__ rxw)
{
  __shared__ float s_eW1[10*128];
  __shared__ float s_eb1[128], s_eW2[128];
  __shared__ float s_rU[256], s_rW2[256];
  int tid = threadIdx.x;
  for (int i = tid; i < 1280; i += 256) s_eW1[i] = eW1[i];
  if (tid < 128){ s_eb1[tid]=eb1[tid]; s_eW2[tid]=eW2[tid]; }
  for (int i=tid;i<256;i+=256){ s_rU[i]=rW1[256*256+i]; s_rW2[i]=rW2[i]; }
  __syncthreads();
  float eb2v = eb2[0], rb2v = rb2[0];
  int lane = tid & 63;
  int gw = blockIdx.x*4 + (tid>>6);
  int nw = gridDim.x*4;
  const float ISIG[10] = {1e-0f,1e-2f,1e-4f,1e-6f,1e-8f,1e-10f,
                          1e-12f,1e-14f,1e-16f,1e-18f};
  int e = gw;
  int s=0, d=0;
  float4 p4 = make_float4(0,0,0,0), q4 = p4;
  float xa0=0,xa1=0,xa2=0,xb0=0,xb1=0,xb2=0;
  if (e < N_EDGES){
    s = srcS[e]; d = dstS[e];
    p4 = *reinterpret_cast<const float4*>(P + (size_t)s*256 + lane*4);
    q4 = *reinterpret_cast<const float4*>(Q + (size_t)d*256 + lane*4);
    xa0=x[s*3+0]; xa1=x[s*3+1]; xa2=x[s*3+2];
    xb0=x[d*3+0]; xb1=x[d*3+1]; xb2=x[d*3+2];
  }
  for (; e < N_EDGES; e += nw){
    int en = e + nw;
    int sn=0, dn=0;
    float4 p4n = make_float4(0,0,0,0), q4n = p4n;
    float ya0=0,ya1=0,ya2=0,yb0=0,yb1=0,yb2=0;
    if (en < N_EDGES){
      sn = srcS[en]; dn = dstS[en];
      p4n = *reinterpret_cast<const float4*>(P + (size_t)sn*256 + lane*4);
      q4n = *reinterpret_cast<const float4*>(Q + (size_t)dn*256 + lane*4);
      ya0=x[sn*3+0]; ya1=x[sn*3+1]; ya2=x[sn*3+2];
      yb0=x[dn*3+0]; yb1=x[dn*3+1]; yb2=x[dn*3+2];
    }
    float xd0 = xa0-xb0, xd1 = xa1-xb1, xd2 = xa2-xb2;
    float d2 = xd0*xd0 + xd1*xd1 + xd2*xd2;
    float g[10];
    #pragma unroll
    for (int j=0;j<10;++j) g[j] = __expf(-d2*ISIG[j]);
    int c1 = lane, c2 = lane+64;
    float h1 = s_eb1[c1], h2 = s_eb1[c2];
    #pragma unroll
    for (int j=0;j<10;++j){ h1 += g[j]*s_eW1[j*128+c1]; h2 += g[j]*s_eW1[j*128+c2]; }
    h1 = lrelu(h1); h2 = lrelu(h2);
    float part = h1*s_eW2[c1] + h2*s_eW2[c2];
    #pragma unroll
    for (int m=1;m<64;m<<=1) part += __shfl_xor(part, m);
    float wlap = part + eb2v; wlap = wlap > 0.f ? wlap : 0.f;
    const float4 u4 = *reinterpret_cast<const float4*>(s_rU + lane*4);
    const float4 w4 = *reinterpret_cast<const float4*>(s_rW2 + lane*4);
    float acc = lrelu(p4.x + q4.x + wlap*u4.x) * w4.x
              + lrelu(p4.y + q4.y + wlap*u4.y) * w4.y
              + lrelu(p4.z + q4.z + wlap*u4.z) * w4.z
              + lrelu(p4.w + q4.w + wlap*u4.w) * w4.w;
    #pragma unroll
    for (int m=1;m<64;m<<=1) acc += __shfl_xor(acc, m);
    float r = acc + rb2v;
    if (lane==0){
      atomicAdd(&deg[s], wlap);
      rxw[e] = make_float4(r*xd0, r*xd1, r*xd2, wlap);
    }
    s=sn; d=dn; p4=p4n; q4=q4n;
    xa0=ya0; xa1=ya1; xa2=ya2; xb0=yb0; xb1=yb1; xb2=yb2;
  }
}

// normE with fused dinv
__global__ void k_normE(const int* __restrict__ srcS, const int* __restrict__ dstS,
                        const float4* __restrict__ rxw, const float* __restrict__ deg,
                        float* __restrict__ norm){
  int e = blockIdx.x*blockDim.x + threadIdx.x;
  if (e < N_EDGES){
    float ds = deg[srcS[e]], dd = deg[dstS[e]];
    float is = ds > 0.f ? rsqrtf(ds) : 0.f;
    float id = dd > 0.f ? rsqrtf(dd) : 0.f;
    norm[e] = is * rxw[e].w * id;
  }
}

// agg pull: wave per node
__global__ __launch_bounds__(256) void k_agg(const int* __restrict__ rowptr,
    const float4* __restrict__ rxw, const float* __restrict__ x, float* __restrict__ outX){
  int lane = threadIdx.x & 63;
  int v = blockIdx.x*4 + (threadIdx.x>>6);
  if (v >= N_NODES) return;
  int b = rowptr[v], e = rowptr[v+1];
  float a0=0.f,a1=0.f,a2=0.f;
  for (int i=b+lane;i<e;i+=64){ float4 f = rxw[i]; a0+=f.x; a1+=f.y; a2+=f.z; }
  #pragma unroll
  for (int m=1;m<64;m<<=1){ a0+=__shfl_xor(a0,m); a1+=__shfl_xor(a1,m); a2+=__shfl_xor(a2,m); }
  if (lane==0){
    int cnt = e-b; if (cnt < 1) cnt = 1;
    float inv = 1.0f/(float)cnt;
    outX[v*3+0] = x[v*3+0] + a0*inv;
    outX[v*3+1] = x[v*3+1] + a1*inv;
    outX[v*3+2] = x[v*3+2] + a2*inv;
  }
}

// polynomial coefficients + run flags: out = sum_j coef_j A^j h0 ; also writes T outputs
// flags[j]   : run k_ax step j (sum_{m>=j}|coef|>0); flags[0] forced 1 (outH must be written)
// flags[16+j]: scaleOnly (zin identically zero: sum_{m>j}|coef| == 0)
__global__ void k_coef(const float* __restrict__ temp, float* __restrict__ coef,
                       int* __restrict__ flags,
                       float* __restrict__ outT1, float* __restrict__ outT2){
  if (threadIdx.x == 0 && blockIdx.x == 0){
    const double binom[11] = {1,10,45,120,210,252,210,120,45,10,1};
    double a[11]; for (int j=0;j<11;++j) a[j]=0.0;
    for (int m=0;m<=10;++m){
      double p[11]; p[0]=1.0; for (int j=1;j<11;++j) p[j]=0.0;
      for (int r2=0;r2<10-m;++r2) for (int j=10;j>=1;--j) p[j]+=p[j-1];
      for (int r2=0;r2<m;++r2)    for (int j=10;j>=1;--j) p[j]-=p[j-1];
      float t = temp[m];
      double c = (binom[m]/1024.0) * (t > 0.f ? (double)t : 0.0);
      for (int j=0;j<11;++j) a[j]+=c*p[j];
    }
    for (int j=0;j<11;++j) coef[j]=(float)a[j];
    double sIn = 0.0;
    for (int j=10;j>=0;--j){
      double sOut = sIn + fabs(a[j]);
      flags[j]    = (sOut != 0.0) ? 1 : 0;
      flags[16+j] = (sIn  == 0.0) ? 1 : 0;
      sIn = sOut;
    }
    flags[0] = 1;  // always write the final output
  }
  int i = threadIdx.x;
  if (blockIdx.x==0 && i < 11){ float t = temp[i]; t = t>0.f?t:0.f; outT1[i]=t; outT2[i]=t; }
}

// zout[v] = coef[j]*h0[v] + sum_{in-edges} norm_e * zin[src]; grid-stride, flag-gated
__global__ __launch_bounds__(256) void k_ax(const int* __restrict__ rowptr,
    const int* __restrict__ srcS, const float* __restrict__ norm,
    const float* __restrict__ zin, const float* __restrict__ h0,
    const float* __restrict__ coef, const int* __restrict__ flags, int j,
    float* __restrict__ zout)
{
  if (!flags[j]) return;
  bool scaleOnly = flags[16+j] != 0;
  float c = coef[j];
  int t = threadIdx.x & 127, sub = threadIdx.x >> 7;
  for (int v = blockIdx.x*2 + sub; v < N_NODES; v += gridDim.x*2){
    float acc0 = c * h0[(size_t)v*128 + t];
    if (!scaleOnly){
      int b = rowptr[v], e2 = rowptr[v+1];
      float acc1 = 0.f;
      int i = b;
      for (; i+1 < e2; i += 2){
        int s0 = srcS[i], s1 = srcS[i+1];
        float n0 = norm[i], n1 = norm[i+1];
        acc0 += n0 * zin[(size_t)s0*128 + t];
        acc1 += n1 * zin[(size_t)s1*128 + t];
      }
      if (i < e2) acc0 += norm[i]*zin[(size_t)srcS[i]*128 + t];
      acc0 += acc1;
    }
    zout[(size_t)v*128 + t] = acc0;
  }
}

extern "C" void kernel_launch(void* const* d_in, const int* in_sizes, int n_in,
                              void* d_out, int out_size, void* d_ws, size_t ws_size,
                              hipStream_t stream) {
  const float* x1  = (const float*)d_in[0];
  const float* h1  = (const float*)d_in[1];
  const float* x2  = (const float*)d_in[2];
  const float* h2  = (const float*)d_in[3];
  const float* eW1 = (const float*)d_in[4];
  const float* eb1 = (const float*)d_in[5];
  const float* eW2 = (const float*)d_in[6];
  const float* eb2 = (const float*)d_in[7];
  const float* rW1 = (const float*)d_in[8];
  const float* rb1 = (const float*)d_in[9];
  const float* rW2 = (const float*)d_in[10];
  const float* rb2 = (const float*)d_in[11];
  const float* fW1 = (const float*)d_in[12];
  const float* fb1 = (const float*)d_in[13];
  const float* fW2 = (const float*)d_in[14];
  const float* fb2 = (const float*)d_in[15];
  const float* temp= (const float*)d_in[16];
  const int* ei1 = (const int*)d_in[17];
  const int* ei2 = (const int*)d_in[18];

  float* out = (float*)d_out;
  float* outX1 = out;
  float* outH1 = out + 60000;
  float* outX2 = out + 2620000;
  float* outH2 = out + 2680000;
  float* outT1 = out + 5240000;
  float* outT2 = out + 5240011;

  char* ws = (char*)d_ws;
  size_t off = 0;
  auto alloc = [&](size_t bytes)->void*{
    void* p = ws + off; off += (bytes + 255) & ~(size_t)255; return p;
  };
  float* P      = (float*)alloc((size_t)N_NODES*256*4);  // later: [t_bf .. | z1]
  float* Q      = (float*)alloc((size_t)N_NODES*256*4);  // later: [h0 | z0]
  unsigned short* h_bf = (unsigned short*)alloc((size_t)N_NODES*128*2);
  unsigned short* WTpq = (unsigned short*)alloc((size_t)512*128*2);
  unsigned short* WTf1 = (unsigned short*)alloc((size_t)128*128*2);
  unsigned short* WTf2 = (unsigned short*)alloc((size_t)128*128*2);
  int*   srcS   = (int*)  alloc((size_t)N_EDGES*4);
  int*   dstS   = (int*)  alloc((size_t)N_EDGES*4);
  float* normE  = (float*)alloc((size_t)N_EDGES*4);
  float4* rxw   = (float4*)alloc((size_t)N_EDGES*16);
  int*   counts = (int*)  alloc((size_t)N_NODES*4);
  int*   rowptr = (int*)  alloc((size_t)(N_NODES+1)*4);
  float* deg    = (float*)alloc((size_t)N_NODES*4);
  float* coef   = (float*)alloc(256);
  int*   flags  = (int*)  alloc(256);

  unsigned short* t_bf = (unsigned short*)P;             // 5.12 MB
  float* z1   = P + (size_t)N_NODES*128;                 // second half of P region
  float* h0   = Q;
  float* z0   = Q + (size_t)N_NODES*128;

  // one-time: polynomial coefficients/flags + T outputs + weight transposes
  k_coef<<<1, 64, 0, stream>>>(temp, coef, flags, outT1, outT2);
  k_prep<<<384, 256, 0, stream>>>(rW1, fW1, fW2, WTpq, WTf1, WTf2);

  const int EB = (N_EDGES + 255)/256;   // 1250
  const int NB = (N_NODES + 255)/256;   // 79

  for (int g = 0; g < 2; ++g){
    const float* x = g ? x2 : x1;
    const float* h = g ? h2 : h1;
    const int* src = g ? ei2 : ei1;
    const int* dst = src + N_EDGES;
    float* outX = g ? outX2 : outX1;
    float* outH = g ? outH2 : outH1;

    // CSR by dst
    k_zero <<<NB, 256, 0, stream>>>(counts, deg);
    k_count<<<EB, 256, 0, stream>>>(dst, counts);
    k_scan <<<1, 256, 0, stream>>>(counts, rowptr);
    k_fill <<<EB, 256, 0, stream>>>(src, dst, rowptr, counts, srcS, dstS);

    // h -> bf16
    k_tobf16<<<2500, 256, 0, stream>>>(h, h_bf);

    // P|Q = h_bf @ WTpq^T (+rb1 on P)
    k_gemm_mfma<<<dim3(313,8), 256, 0, stream>>>(h_bf, WTpq, rb1, 0, P, Q, nullptr);

    // per-edge wlap + r
    k_edge<<<4096, 256, 0, stream>>>(srcS, dstS, x, P, Q, eW1, eb1, eW2, eb2,
                                     rW1, rW2, rb2, deg, rxw);
    k_normE<<<EB, 256, 0, stream>>>(srcS, dstS, rxw, deg, normE);

    // x output
    k_agg<<<5000, 256, 0, stream>>>(rowptr, rxw, x, outX);

    // f-MLP: t_bf = bf16(lrelu(h_bf@fW1+fb1)); h0 = t_bf@fW2+fb2   (P region dead)
    k_gemm_mfma<<<dim3(313,2), 256, 0, stream>>>(h_bf, WTf1, fb1, 1, nullptr, nullptr, t_bf);
    k_gemm_mfma<<<dim3(313,2), 256, 0, stream>>>(t_bf, WTf2, fb2, 2, h0, nullptr, nullptr);

    // Horner: j=10..0 (j=10 is the scaleOnly init; zero-coef steps exit in ~µs)
    for (int j = 10; j >= 0; --j){
      float* zi = (j==10) ? z1 : (((10-(j+1)) & 1) ? z1 : z0);
      float* zo = (j==0)  ? outH : (((10-j) & 1) ? z1 : z0);
      k_ax<<<2500, 256, 0, stream>>>(rowptr, srcS, normE, zi, h0, coef, flags, j, zo);
    }
  }
  (void)in_sizes; (void)n_in; (void)out_size; (void)ws_size;
}

// Round 4
// 448.128 us; speedup vs baseline: 3.2586x; 1.2907x over previous
//
#include <hip/hip_runtime.h>
#include <math.h>

#define N_NODES 20000
#define N_EDGES 320000

__device__ __forceinline__ float lrelu(float x){ return x > 0.f ? x : 0.02f*x; }

__device__ __forceinline__ unsigned short f2bf(float f){
  union { float f; unsigned u; } v; v.f = f;
  unsigned r = (v.u + 0x7FFFu + ((v.u >> 16) & 1u)) >> 16;
  return (unsigned short)r;
}
__device__ __forceinline__ float bf2f(unsigned short u){
  union { unsigned u; float f; } v; v.u = ((unsigned)u) << 16; return v.f;
}

typedef __attribute__((ext_vector_type(8))) short bf16x8;
typedef __attribute__((ext_vector_type(4))) float f32x4;
typedef __attribute__((ext_vector_type(8))) unsigned short u16x8;

// ---------------- CSR build ----------------
__global__ void k_zero(int* counts, float* deg){
  int i = blockIdx.x*blockDim.x + threadIdx.x;
  if (i < N_NODES){ counts[i]=0; deg[i]=0.f; }
}

// fused: h->bf16 convert (640000 float4 groups) + dst-degree count
__global__ void k_cnt_cvt(const int* __restrict__ dst, int* __restrict__ counts,
                          const float* __restrict__ h, unsigned short* __restrict__ h_bf){
  int i = blockIdx.x*256 + threadIdx.x;      // exactly 640000 threads
  float4 v = reinterpret_cast<const float4*>(h)[i];
  ushort4 o;
  o.x = f2bf(v.x); o.y = f2bf(v.y); o.z = f2bf(v.z); o.w = f2bf(v.w);
  reinterpret_cast<ushort4*>(h_bf)[i] = o;
  if (i < N_EDGES) atomicAdd(&counts[dst[i]], 1);
}

__global__ void k_scan(int* __restrict__ counts, int* __restrict__ rowptr){
  __shared__ int part[256];
  int tid = threadIdx.x;
  const int CH = (N_NODES + 255)/256; // 79
  int b = tid*CH, e = b+CH; if (e > N_NODES) e = N_NODES;
  int s = 0;
  for (int i=b;i<e;++i) s += counts[i];
  part[tid] = s; __syncthreads();
  if (tid==0){
    int run=0;
    for (int i=0;i<256;++i){ int t=part[i]; part[i]=run; run+=t; }
    rowptr[N_NODES]=run;
  }
  __syncthreads();
  int off = part[tid];
  for (int i=b;i<e;++i){ rowptr[i]=off; off += counts[i]; counts[i]=0; }
}

__global__ void k_fill(const int* __restrict__ src, const int* __restrict__ dst,
                       const int* __restrict__ rowptr, int* __restrict__ cursor,
                       int* __restrict__ srcS, int* __restrict__ dstS){
  int e = blockIdx.x*blockDim.x + threadIdx.x;
  if (e < N_EDGES){
    int d = dst[e];
    int pos = atomicAdd(&cursor[d],1);
    int idx = rowptr[d] + pos;
    srcS[idx] = src[e];
    dstS[idx] = d;
  }
}

// ---------------- weight prep: WTbig[640][128], WTf2[128][128] bf16 (once) -----
__global__ void k_prep(const float* __restrict__ rW1, const float* __restrict__ fW1,
                       const float* __restrict__ fW2,
                       unsigned short* __restrict__ WTbig,
                       unsigned short* __restrict__ WTf2){
  int i = blockIdx.x*blockDim.x + threadIdx.x;   // 98304 total
  if (i < 81920){
    int row = i >> 7, k = i & 127;
    float v = (row < 256) ? rW1[(size_t)k*256 + row]
            : (row < 512) ? rW1[(size_t)(128+k)*256 + (row-256)]
                          : fW1[(size_t)k*128 + (row-512)];
    WTbig[i] = f2bf(v);
  } else if (i < 98304){
    int j = i - 81920; int n = j >> 7, k = j & 127;
    WTf2[j] = f2bf(fW2[(size_t)k*128 + n]);
  }
}

// ---------------- MFMA bf16 GEMM: 64x64 tile, 4 waves, 16x16x32 ----------------
// mode 0 (N=640): col<256 -> Pb=bf16(v+b0[col]); col<512 -> Qb=bf16(v);
//                 else Tb=bf16(lrelu(v+b1[col-512]))
// mode 1 (N=128): O1 = v + b0[col]  (f32, stride 128)
__global__ __launch_bounds__(256) void k_gemm_mfma(
    const unsigned short* __restrict__ Abf, const unsigned short* __restrict__ WT,
    const float* __restrict__ b0, const float* __restrict__ b1, int mode,
    float* __restrict__ O1, unsigned short* __restrict__ Pb,
    unsigned short* __restrict__ Qb, unsigned short* __restrict__ Tb)
{
  __shared__ char lA[16384];
  __shared__ char lB[16384];
  int t = threadIdx.x;
  int rbase = blockIdx.x * 64;
  int cbase = blockIdx.y * 64;
  #pragma unroll
  for (int i=0;i<4;++i){
    int c = t + i*256;            // chunk 0..1023, 16B each
    int row = c >> 4, c8 = c & 15;
    int grow = rbase + row; if (grow > N_NODES-1) grow = N_NODES-1;
    float4 av = *reinterpret_cast<const float4*>(Abf + (size_t)grow*128 + c8*8);
    *reinterpret_cast<float4*>(lA + (((row<<8) + (c8<<4)) ^ ((row&7)<<4))) = av;
    float4 wv = *reinterpret_cast<const float4*>(WT + (size_t)(cbase+row)*128 + c8*8);
    *reinterpret_cast<float4*>(lB + (((row<<8) + (c8<<4)) ^ ((row&7)<<4))) = wv;
  }
  __syncthreads();
  int l = t & 63, w = t >> 6;
  int lr = l & 15;
  int lkb = ((l >> 4) << 3) * 2;          // k byte offset: 0,16,32,48
  int sxor = (lr & 7) << 4;
  f32x4 acc[4];
  #pragma unroll
  for (int tm=0;tm<4;++tm) acc[tm] = (f32x4){0.f,0.f,0.f,0.f};
  #pragma unroll
  for (int ks=0; ks<4; ++ks){
    int kb = ks*64 + lkb;
    bf16x8 bv = *reinterpret_cast<const bf16x8*>(lB + (((((w<<4)+lr)<<8) + kb) ^ sxor));
    #pragma unroll
    for (int tm=0;tm<4;++tm){
      bf16x8 av = *reinterpret_cast<const bf16x8*>(lA + (((((tm<<4)+lr)<<8) + kb) ^ sxor));
      acc[tm] = __builtin_amdgcn_mfma_f32_16x16x32_bf16(av, bv, acc[tm], 0, 0, 0);
    }
  }
  int col = cbase + (w<<4) + lr;
  float bval;
  if (mode==0) bval = (col < 256) ? b0[col] : (col >= 512 ? b1[col-512] : 0.f);
  else         bval = b0[col];
  int rsub = (l >> 4) << 2;
  #pragma unroll
  for (int tm=0;tm<4;++tm){
    #pragma unroll
    for (int r=0;r<4;++r){
      int grow = rbase + (tm<<4) + rsub + r;
      if (grow < N_NODES){
        float v = acc[tm][r];
        if (mode==0){
          if (col < 256)      Pb[(size_t)grow*256 + col]       = f2bf(v + bval);
          else if (col < 512) Qb[(size_t)grow*256 + col - 256] = f2bf(v);
          else                Tb[(size_t)grow*128 + col - 512] = f2bf(lrelu(v + bval));
        } else {
          O1[(size_t)grow*128 + col] = v + bval;
        }
      }
    }
  }
}

// ---------------- per-edge: 16 lanes/edge, bf16 P/Q gathers ----------------
__global__ __launch_bounds__(256) void k_edge(
    const int* __restrict__ srcS, const int* __restrict__ dstS,
    const float* __restrict__ x,
    const unsigned short* __restrict__ P, const unsigned short* __restrict__ Q,
    const float* __restrict__ eW1, const float* __restrict__ eb1,
    const float* __restrict__ eW2, const float* __restrict__ eb2,
    const float* __restrict__ rW1, const float* __restrict__ rW2,
    const float* __restrict__ rb2,
    float* __restrict__ deg, float4* __restrict__ rxw)
{
  __shared__ float s_eW1[1280];
  int tid = threadIdx.x;
  for (int i = tid; i < 1280; i += 256) s_eW1[i] = eW1[i];
  __syncthreads();
  int l = tid & 15;            // lane in 16-lane edge group
  int grp = tid >> 4;          // 0..15 edge slot in block
  // per-lane weight registers
  float eb1v[8], eW2v[8];
  #pragma unroll
  for (int i=0;i<4;++i){
    float2 b = *reinterpret_cast<const float2*>(eb1 + 2*l + 32*i);
    float2 w = *reinterpret_cast<const float2*>(eW2 + 2*l + 32*i);
    eb1v[2*i]=b.x; eb1v[2*i+1]=b.y; eW2v[2*i]=w.x; eW2v[2*i+1]=w.y;
  }
  float rUa[16], rW2a[16];
  #pragma unroll
  for (int i=0;i<4;++i){
    float4 u = *reinterpret_cast<const float4*>(rW1 + 256*256 + l*16 + 4*i);
    float4 w = *reinterpret_cast<const float4*>(rW2 + l*16 + 4*i);
    rUa[4*i]=u.x; rUa[4*i+1]=u.y; rUa[4*i+2]=u.z; rUa[4*i+3]=u.w;
    rW2a[4*i]=w.x; rW2a[4*i+1]=w.y; rW2a[4*i+2]=w.z; rW2a[4*i+3]=w.w;
  }
  float eb2v = eb2[0], rb2v = rb2[0];
  for (int e = blockIdx.x*16 + grp; e < N_EDGES; e += gridDim.x*16){
    int s = srcS[e], d = dstS[e];
    // issue bf16 gathers early (independent of wlap)
    const u16x8* Ps = reinterpret_cast<const u16x8*>(P + (size_t)s*256 + l*16);
    const u16x8* Qd = reinterpret_cast<const u16x8*>(Q + (size_t)d*256 + l*16);
    u16x8 pa = Ps[0], pb = Ps[1];
    u16x8 qa = Qd[0], qb = Qd[1];
    float dx0 = x[s*3+0]-x[d*3+0];
    float dx1 = x[s*3+1]-x[d*3+1];
    float dx2 = x[s*3+2]-x[d*3+2];
    float d2 = dx0*dx0 + dx1*dx1 + dx2*dx2;
    // h-MLP: this lane's 8 hidden cols {2l,2l+1} + 32i
    float h[8];
    #pragma unroll
    for (int i=0;i<8;++i) h[i] = eb1v[i];
    const float IS[10] = {1.f,1e-2f,1e-4f,1e-6f,1e-8f,1e-10f,
                          1e-12f,1e-14f,1e-16f,1e-18f};
    #pragma unroll
    for (int j=0;j<10;++j){
      float gj = __expf(-d2*IS[j]);
      #pragma unroll
      for (int i=0;i<4;++i){
        float2 w2 = *reinterpret_cast<const float2*>(&s_eW1[j*128 + 2*l + 32*i]);
        h[2*i]   += gj*w2.x;
        h[2*i+1] += gj*w2.y;
      }
    }
    float part = 0.f;
    #pragma unroll
    for (int i=0;i<8;++i) part += lrelu(h[i])*eW2v[i];
    part += __shfl_xor(part,1); part += __shfl_xor(part,2);
    part += __shfl_xor(part,4); part += __shfl_xor(part,8);
    float wlap = part + eb2v; wlap = wlap > 0.f ? wlap : 0.f;
    // r-dot: this lane's 16 of 256 cols (contiguous l*16)
    float acc = 0.f;
    #pragma unroll
    for (int k=0;k<8;++k){
      float p = bf2f((unsigned short)pa[k]);
      float q = bf2f((unsigned short)qa[k]);
      acc += lrelu(p + q + wlap*rUa[k]) * rW2a[k];
    }
    #pragma unroll
    for (int k=0;k<8;++k){
      float p = bf2f((unsigned short)pb[k]);
      float q = bf2f((unsigned short)qb[k]);
      acc += lrelu(p + q + wlap*rUa[8+k]) * rW2a[8+k];
    }
    acc += __shfl_xor(acc,1); acc += __shfl_xor(acc,2);
    acc += __shfl_xor(acc,4); acc += __shfl_xor(acc,8);
    if (l==0){
      float r = acc + rb2v;
      atomicAdd(&deg[s], wlap);
      rxw[e] = make_float4(r*dx0, r*dx1, r*dx2, wlap);
    }
  }
}

// ---------------- fused post pass: agg (blocks 0..4999) + normE (5000..6249) ----
__global__ __launch_bounds__(256) void k_post(const int* __restrict__ rowptr,
    const float4* __restrict__ rxw, const float* __restrict__ x,
    float* __restrict__ outX,
    const int* __restrict__ srcS, const int* __restrict__ dstS,
    const float* __restrict__ deg, float* __restrict__ norm)
{
  if (blockIdx.x < 5000){
    int lane = threadIdx.x & 63;
    int v = blockIdx.x*4 + (threadIdx.x>>6);
    if (v >= N_NODES) return;
    int b = rowptr[v], e = rowptr[v+1];
    float a0=0.f,a1=0.f,a2=0.f;
    for (int i=b+lane;i<e;i+=64){ float4 f = rxw[i]; a0+=f.x; a1+=f.y; a2+=f.z; }
    #pragma unroll
    for (int m=1;m<64;m<<=1){ a0+=__shfl_xor(a0,m); a1+=__shfl_xor(a1,m); a2+=__shfl_xor(a2,m); }
    if (lane==0){
      int cnt = e-b; if (cnt < 1) cnt = 1;
      float inv = 1.0f/(float)cnt;
      outX[v*3+0] = x[v*3+0] + a0*inv;
      outX[v*3+1] = x[v*3+1] + a1*inv;
      outX[v*3+2] = x[v*3+2] + a2*inv;
    }
  } else {
    int e = (blockIdx.x-5000)*256 + threadIdx.x;
    if (e < N_EDGES){
      float ds = deg[srcS[e]], dd = deg[dstS[e]];
      float is = ds > 0.f ? rsqrtf(ds) : 0.f;
      float id = dd > 0.f ? rsqrtf(dd) : 0.f;
      norm[e] = is * rxw[e].w * id;
    }
  }
}

// polynomial coefficients + run flags
__global__ void k_coef(const float* __restrict__ temp, float* __restrict__ coef,
                       int* __restrict__ flags,
                       float* __restrict__ outT1, float* __restrict__ outT2){
  if (threadIdx.x == 0 && blockIdx.x == 0){
    const double binom[11] = {1,10,45,120,210,252,210,120,45,10,1};
    double a[11]; for (int j=0;j<11;++j) a[j]=0.0;
    for (int m=0;m<=10;++m){
      double p[11]; p[0]=1.0; for (int j=1;j<11;++j) p[j]=0.0;
      for (int r2=0;r2<10-m;++r2) for (int j=10;j>=1;--j) p[j]+=p[j-1];
      for (int r2=0;r2<m;++r2)    for (int j=10;j>=1;--j) p[j]-=p[j-1];
      float t = temp[m];
      double c = (binom[m]/1024.0) * (t > 0.f ? (double)t : 0.0);
      for (int j=0;j<11;++j) a[j]+=c*p[j];
    }
    for (int j=0;j<11;++j) coef[j]=(float)a[j];
    double sIn = 0.0;
    for (int j=10;j>=0;--j){
      double sOut = sIn + fabs(a[j]);
      flags[j]    = (sOut != 0.0) ? 1 : 0;
      flags[16+j] = (sIn  == 0.0) ? 1 : 0;
      sIn = sOut;
    }
    flags[0] = 1;  // always write the final output
  }
  int i = threadIdx.x;
  if (blockIdx.x==0 && i < 11){ float t = temp[i]; t = t>0.f?t:0.f; outT1[i]=t; outT2[i]=t; }
}

// zout[v] = coef[j]*h0[v] + sum_{in-edges} norm_e * zin[src]; grid-stride, flag-gated
__global__ __launch_bounds__(256) void k_ax(const int* __restrict__ rowptr,
    const int* __restrict__ srcS, const float* __restrict__ norm,
    const float* __restrict__ zin, const float* __restrict__ h0,
    const float* __restrict__ coef, const int* __restrict__ flags, int j,
    float* __restrict__ zout)
{
  if (!flags[j]) return;
  bool scaleOnly = flags[16+j] != 0;
  float c = coef[j];
  int t = threadIdx.x & 127, sub = threadIdx.x >> 7;
  for (int v = blockIdx.x*2 + sub; v < N_NODES; v += gridDim.x*2){
    float acc0 = c * h0[(size_t)v*128 + t];
    if (!scaleOnly){
      int b = rowptr[v], e2 = rowptr[v+1];
      float acc1 = 0.f;
      int i = b;
      for (; i+1 < e2; i += 2){
        int s0 = srcS[i], s1 = srcS[i+1];
        float n0 = norm[i], n1 = norm[i+1];
        acc0 += n0 * zin[(size_t)s0*128 + t];
        acc1 += n1 * zin[(size_t)s1*128 + t];
      }
      if (i < e2) acc0 += norm[i]*zin[(size_t)srcS[i]*128 + t];
      acc0 += acc1;
    }
    zout[(size_t)v*128 + t] = acc0;
  }
}

extern "C" void kernel_launch(void* const* d_in, const int* in_sizes, int n_in,
                              void* d_out, int out_size, void* d_ws, size_t ws_size,
                              hipStream_t stream) {
  const float* x1  = (const float*)d_in[0];
  const float* h1  = (const float*)d_in[1];
  const float* x2  = (const float*)d_in[2];
  const float* h2  = (const float*)d_in[3];
  const float* eW1 = (const float*)d_in[4];
  const float* eb1 = (const float*)d_in[5];
  const float* eW2 = (const float*)d_in[6];
  const float* eb2 = (const float*)d_in[7];
  const float* rW1 = (const float*)d_in[8];
  const float* rb1 = (const float*)d_in[9];
  const float* rW2 = (const float*)d_in[10];
  const float* rb2 = (const float*)d_in[11];
  const float* fW1 = (const float*)d_in[12];
  const float* fb1 = (const float*)d_in[13];
  const float* fW2 = (const float*)d_in[14];
  const float* fb2 = (const float*)d_in[15];
  const float* temp= (const float*)d_in[16];
  const int* ei1 = (const int*)d_in[17];
  const int* ei2 = (const int*)d_in[18];

  float* out = (float*)d_out;
  float* outX1 = out;
  float* outH1 = out + 60000;
  float* outX2 = out + 2620000;
  float* outH2 = out + 2680000;
  float* outT1 = out + 5240000;
  float* outT2 = out + 5240011;

  char* ws = (char*)d_ws;
  size_t off = 0;
  auto alloc = [&](size_t bytes)->void*{
    void* p = ws + off; off += (bytes + 255) & ~(size_t)255; return p;
  };
  unsigned short* Pb   = (unsigned short*)alloc((size_t)N_NODES*256*2);  // z1 aliases
  unsigned short* Qb   = (unsigned short*)alloc((size_t)N_NODES*256*2);
  unsigned short* h_bf = (unsigned short*)alloc((size_t)N_NODES*128*2);  // z0 aliases (with t_bf)
  unsigned short* t_bf = (unsigned short*)alloc((size_t)N_NODES*128*2);
  float* h0     = (float*)alloc((size_t)N_NODES*128*4);
  unsigned short* WTbig= (unsigned short*)alloc((size_t)640*128*2);
  unsigned short* WTf2 = (unsigned short*)alloc((size_t)128*128*2);
  int*   srcS   = (int*)  alloc((size_t)N_EDGES*4);
  int*   dstS   = (int*)  alloc((size_t)N_EDGES*4);
  float* normE  = (float*)alloc((size_t)N_EDGES*4);
  float4* rxw   = (float4*)alloc((size_t)N_EDGES*16);
  int*   counts = (int*)  alloc((size_t)N_NODES*4);
  int*   rowptr = (int*)  alloc((size_t)(N_NODES+1)*4);
  float* deg    = (float*)alloc((size_t)N_NODES*4);
  float* coef   = (float*)alloc(256);
  int*   flags  = (int*)  alloc(256);

  float* z0 = (float*)h_bf;   // spans h_bf + t_bf = 10,240,000 B (both dead by k_ax)
  float* z1 = (float*)Pb;     // 10,240,000 B (dead after k_edge)

  // one-time: polynomial coefficients/flags + T outputs + weight transposes
  k_coef<<<1, 64, 0, stream>>>(temp, coef, flags, outT1, outT2);
  k_prep<<<384, 256, 0, stream>>>(rW1, fW1, fW2, WTbig, WTf2);

  const int EB = (N_EDGES + 255)/256;   // 1250
  const int NB = (N_NODES + 255)/256;   // 79

  for (int g = 0; g < 2; ++g){
    const float* x = g ? x2 : x1;
    const float* h = g ? h2 : h1;
    const int* src = g ? ei2 : ei1;
    const int* dst = src + N_EDGES;
    float* outX = g ? outX2 : outX1;
    float* outH = g ? outH2 : outH1;

    // CSR by dst (+ h->bf16 fused with count)
    k_zero   <<<NB, 256, 0, stream>>>(counts, deg);
    k_cnt_cvt<<<2500, 256, 0, stream>>>(dst, counts, h, h_bf);
    k_scan   <<<1, 256, 0, stream>>>(counts, rowptr);
    k_fill   <<<EB, 256, 0, stream>>>(src, dst, rowptr, counts, srcS, dstS);

    // [P | Q | t] = h_bf @ WTbig^T (biases/activations per col-range), bf16 out
    k_gemm_mfma<<<dim3(313,10), 256, 0, stream>>>(h_bf, WTbig, rb1, fb1, 0,
                                                  nullptr, Pb, Qb, t_bf);
    // h0 = t_bf @ WTf2^T + fb2 (f32)
    k_gemm_mfma<<<dim3(313,2), 256, 0, stream>>>(t_bf, WTf2, fb2, nullptr, 1,
                                                 h0, nullptr, nullptr, nullptr);

    // per-edge wlap + r (16 lanes/edge)
    k_edge<<<2500, 256, 0, stream>>>(srcS, dstS, x, Pb, Qb, eW1, eb1, eW2, eb2,
                                     rW1, rW2, rb2, deg, rxw);
    // fused agg + normE
    k_post<<<6250, 256, 0, stream>>>(rowptr, rxw, x, outX, srcS, dstS, deg, normE);

    // Horner: j=10..0 (zero-coef steps exit immediately)
    for (int j = 10; j >= 0; --j){
      float* zi = (j==10) ? z1 : (((10-(j+1)) & 1) ? z1 : z0);
      float* zo = (j==0)  ? outH : (((10-j) & 1) ? z1 : z0);
      k_ax<<<2500, 256, 0, stream>>>(rowptr, srcS, normE, zi, h0, coef, flags, j, zo);
    }
  }
  (void)in_sizes; (void)n_in; (void)out_size; (void)ws_size;
}